// Round 6
// baseline (28993.652 us; speedup 1.0000x reference)
//
#include <hip/hip_runtime.h>

#define HN 256
#define QN 64
#define PN 512
#define CH 8

typedef float f4 __attribute__((ext_vector_type(4)));

__device__ __forceinline__ float dot4(f4 a, f4 b) {
  return a.x * b.x + a.y * b.y + a.z * b.z + a.w * b.w;
}
__device__ __forceinline__ float fast_sig(float x) {
  return __builtin_amdgcn_rcpf(1.f + __builtin_amdgcn_exp2f(-1.44269504f * x));
}
__device__ __forceinline__ float fast_tanh(float x) {
  return 1.f - 2.f * __builtin_amdgcn_rcpf(1.f + __builtin_amdgcn_exp2f(2.88539008f * x));
}

struct SMem {
  union {
    float q32[QN][HN];                  // 64KB (prologue only)
    struct {
      alignas(16) float pgc[CH][1024];  // 32KB  Wih[:,0:256] @ p_u
      alignas(16) float wpc[CH][HN];    // 8KB   whp_b + whp_w @ p_u
      alignas(16) float pch[CH][HN];    // 8KB   p rows (f32)
    } c;
  } u;
  alignas(16) float hx[HN];
  float cx[HN];
  alignas(16) float wA[HN];
  float wrb[HN];                        // whr_b staged
  float gates[1024];
  float scores[QN];
  alignas(16) float al[QN];
};
static_assert(sizeof(SMem) <= 160 * 1024, "LDS overflow");

__global__ void __launch_bounds__(1024, 1)
match_kernel(const float* __restrict__ passage, const float* __restrict__ question,
             const float* __restrict__ whq_w, const float* __restrict__ whq_b,
             const float* __restrict__ whp_w, const float* __restrict__ whp_b,
             const float* __restrict__ whr_w, const float* __restrict__ whr_b,
             const float* __restrict__ w_w,
             const float* __restrict__ Wih_f, const float* __restrict__ Whh_f,
             const float* __restrict__ bih_f, const float* __restrict__ bhh_f,
             const float* __restrict__ Wih_b, const float* __restrict__ Whh_b,
             const float* __restrict__ bih_b, const float* __restrict__ bhh_b,
             float* __restrict__ out)
{
  __shared__ SMem sm;
  const int t = threadIdx.x;
  const int bid = blockIdx.x;
  // dir-homogeneous XCD mapping: XCD = bid%8; XCD 0-3 -> dir0, 4-7 -> dir1
  const int e = bid & 7;
  const int dir = e >> 2;
  const int b = ((bid >> 3) << 2) | (e & 3);

  const float* Wih = dir ? Wih_b : Wih_f;
  const float* Whh = dir ? Whh_b : Whh_f;
  const float* bih = dir ? bih_b : bih_f;
  const float* bhh = dir ? bhh_b : bhh_f;

  const int qB = t >> 4;   // 0..63 (phase B q-owner; also row-group base g2)
  const int sg = t & 15;   // 16-lane slice id
  const int g2 = t >> 4;   // row-group base for sliced GEMVs

  // ---------------- prologue 1: stage question[b], init state ----------------
  {
    const int q = t >> 4, c0 = (t & 15) * 16;
    const float* src = question + ((size_t)b * QN + q) * HN + c0;
    #pragma unroll
    for (int m = 0; m < 4; ++m)
      *(f4*)&sm.u.q32[q][c0 + 4 * m] = *(const f4*)(src + 4 * m);
  }
  if (t < HN) { sm.hx[t] = 0.f; sm.cx[t] = 0.f; sm.wrb[t] = whr_b[t]; }
  __syncthreads();

  // ---------------- prologue 2: wq slice (q=qB, h=sg*16+j) into registers ----
  float wqr[16], wwr[16];
  #pragma unroll
  for (int j = 0; j < 16; ++j) {
    wqr[j] = whq_b[sg * 16 + j];
    wwr[j] = w_w[sg * 16 + j];
  }
  for (int k = 0; k < HN; k += 4) {
    f4 qv = *(const f4*)&sm.u.q32[qB][k];
    #pragma unroll
    for (int j = 0; j < 16; ++j) {
      f4 w = *(const f4*)(whq_w + (size_t)(sg * 16 + j) * HN + k);
      wqr[j] += dot4(w, qv);
    }
  }

  // ---------------- prologue 3: Gq[r=t][q] = Wih[r, 256:512] . Q[q] ----------
  float gq[QN];
  #pragma unroll
  for (int q = 0; q < QN; ++q) gq[q] = 0.f;
  {
    const float* wrow = Wih + (size_t)t * 512 + 256;
    for (int i = 0; i < 64; ++i) {
      f4 w = *(const f4*)(wrow + 4 * i);
      #pragma unroll
      for (int q = 0; q < QN; ++q)
        gq[q] += dot4(w, *(const f4*)&sm.u.q32[q][4 * i]);
    }
  }
  const float biasr = bih[t] + bhh[t];
  __syncthreads();   // last readers of q32 done; union reused below

  const int tb = dir ? (PN - 1) : 0;
  const int ts = dir ? -1 : 1;

  for (int s = 0; s < PN; ++s) {
    const int tau = s & (CH - 1);
    if (tau == 0) {
      // ---- stage p chunk ----
      if (t < 512) {
        const int tt = t >> 6, cc = (t & 63) * 4;
        const int trow = tb + ts * (s + tt);
        *(f4*)&sm.u.c.pch[tt][cc] =
            *(const f4*)(passage + ((size_t)b * PN + trow) * HN + cc);
      }
      __syncthreads();
      // ---- wpc[u][h] = whp_b[h] + whp_w[h] . p_u  (rows 256, 4 sliced passes)
      #pragma unroll
      for (int rr = 0; rr < 4; ++rr) {
        const int h = g2 + 64 * rr;
        const float* wrow = whp_w + (size_t)h * HN + sg * 4;
        float acc[CH];
        #pragma unroll
        for (int uu = 0; uu < CH; ++uu) acc[uu] = 0.f;
        #pragma unroll
        for (int m = 0; m < 4; ++m) {
          f4 w = *(const f4*)(wrow + m * 64);
          #pragma unroll
          for (int uu = 0; uu < CH; ++uu)
            acc[uu] += dot4(w, *(const f4*)&sm.u.c.pch[uu][m * 64 + sg * 4]);
        }
        #pragma unroll
        for (int uu = 0; uu < CH; ++uu) {
          acc[uu] += __shfl_xor(acc[uu], 1);
          acc[uu] += __shfl_xor(acc[uu], 2);
          acc[uu] += __shfl_xor(acc[uu], 4);
          acc[uu] += __shfl_xor(acc[uu], 8);
        }
        if (sg == rr) {
          const float pb = whp_b[h];
          #pragma unroll
          for (int uu = 0; uu < CH; ++uu) sm.u.c.wpc[uu][h] = acc[uu] + pb;
        }
      }
      // ---- pgc[u][r] = Wih[r, 0:256] . p_u  (rows 1024, 16 sliced passes) ----
      #pragma unroll
      for (int rr = 0; rr < 16; ++rr) {
        const int r = g2 + 64 * rr;
        const float* wrow = Wih + (size_t)r * 512 + sg * 4;
        float acc[CH];
        #pragma unroll
        for (int uu = 0; uu < CH; ++uu) acc[uu] = 0.f;
        #pragma unroll
        for (int m = 0; m < 4; ++m) {
          f4 w = *(const f4*)(wrow + m * 64);
          #pragma unroll
          for (int uu = 0; uu < CH; ++uu)
            acc[uu] += dot4(w, *(const f4*)&sm.u.c.pch[uu][m * 64 + sg * 4]);
        }
        #pragma unroll
        for (int uu = 0; uu < CH; ++uu) {
          acc[uu] += __shfl_xor(acc[uu], 1);
          acc[uu] += __shfl_xor(acc[uu], 2);
          acc[uu] += __shfl_xor(acc[uu], 4);
          acc[uu] += __shfl_xor(acc[uu], 8);
        }
        if (sg == rr) {
          #pragma unroll
          for (int uu = 0; uu < CH; ++uu) sm.u.c.pgc[uu][r] = acc[uu];
        }
      }
      __syncthreads();
    }

    // ---- Phase A: wA[h] = whr_w[h].hx + wpc[tau][h] + whr_b[h] ----
    #pragma unroll
    for (int rr = 0; rr < 4; ++rr) {
      const int h = g2 + 64 * rr;
      const float* wrow = whr_w + (size_t)h * HN + sg * 4;
      float a = 0.f;
      #pragma unroll
      for (int m = 0; m < 4; ++m)
        a += dot4(*(const f4*)(wrow + m * 64),
                  *(const f4*)&sm.hx[m * 64 + sg * 4]);
      a += __shfl_xor(a, 1);
      a += __shfl_xor(a, 2);
      a += __shfl_xor(a, 4);
      a += __shfl_xor(a, 8);
      if (sg == rr) sm.wA[h] = a + sm.u.c.wpc[tau][h] + sm.wrb[h];
    }
    __syncthreads();

    // ---- Phase B: scores[q] = sum_h tanh(wq[q][h] + wA[h]) * w_vec[h] ----
    {
      float sc = 0.f;
      #pragma unroll
      for (int jj = 0; jj < 4; ++jj) {
        f4 a4 = *(const f4*)&sm.wA[sg * 16 + 4 * jj];
        sc += fast_tanh(wqr[4 * jj + 0] + a4.x) * wwr[4 * jj + 0];
        sc += fast_tanh(wqr[4 * jj + 1] + a4.y) * wwr[4 * jj + 1];
        sc += fast_tanh(wqr[4 * jj + 2] + a4.z) * wwr[4 * jj + 2];
        sc += fast_tanh(wqr[4 * jj + 3] + a4.w) * wwr[4 * jj + 3];
      }
      sc += __shfl_xor(sc, 1);
      sc += __shfl_xor(sc, 2);
      sc += __shfl_xor(sc, 4);
      sc += __shfl_xor(sc, 8);
      if (sg == 0) sm.scores[qB] = sc;
    }
    __syncthreads();

    // ---- Phase C (wave 0) || Phase E1 (all): Whh[r].hx slice-GEMV ----
    #pragma unroll
    for (int rr = 0; rr < 16; ++rr) {
      const int r = g2 + 64 * rr;
      const float* wrow = Whh + (size_t)r * HN + sg * 4;
      float a = 0.f;
      #pragma unroll
      for (int m = 0; m < 4; ++m)
        a += dot4(*(const f4*)(wrow + m * 64),
                  *(const f4*)&sm.hx[m * 64 + sg * 4]);
      a += __shfl_xor(a, 1);
      a += __shfl_xor(a, 2);
      a += __shfl_xor(a, 4);
      a += __shfl_xor(a, 8);
      if (sg == rr) sm.gates[r] = a;
    }
    if (t < 64) {  // softmax over q; w_b dropped (shift-invariant)
      float sv = sm.scores[t];
      float mx = sv;
      #pragma unroll
      for (int o = 1; o < 64; o <<= 1) mx = fmaxf(mx, __shfl_xor(mx, o));
      float ex = __builtin_amdgcn_exp2f(1.44269504f * (sv - mx));
      float sum = ex;
      #pragma unroll
      for (int o = 1; o < 64; o <<= 1) sum += __shfl_xor(sum, o);
      sm.al[t] = ex * __builtin_amdgcn_rcpf(sum);
    }
    __syncthreads();

    // ---- Phase E2: gates[r=t] += pgc + bias + Gq[r].alpha ----
    {
      float acc = sm.gates[t] + sm.u.c.pgc[tau][t] + biasr;
      #pragma unroll
      for (int jj = 0; jj < 16; ++jj) {
        f4 av = *(const f4*)&sm.al[4 * jj];
        acc += gq[4 * jj + 0] * av.x + gq[4 * jj + 1] * av.y
             + gq[4 * jj + 2] * av.z + gq[4 * jj + 3] * av.w;
      }
      sm.gates[t] = acc;
    }
    __syncthreads();

    // ---- Phase F: LSTM elementwise + f32 output ----
    if (t < HN) {
      float gi = sm.gates[t], gf = sm.gates[HN + t];
      float gg = sm.gates[2 * HN + t], go = sm.gates[3 * HN + t];
      float c = fast_sig(gf) * sm.cx[t] + fast_sig(gi) * fast_tanh(gg);
      float hn = fast_sig(go) * fast_tanh(c);
      sm.cx[t] = c;
      sm.hx[t] = hn;
      const int trow = tb + ts * s;
      out[((size_t)trow * 64 + b) * 512 + dir * HN + t] = hn;
    }
    __syncthreads();
  }
}

extern "C" void kernel_launch(void* const* d_in, const int* in_sizes, int n_in,
                              void* d_out, int out_size, void* d_ws, size_t ws_size,
                              hipStream_t stream) {
  (void)in_sizes; (void)n_in; (void)out_size; (void)d_ws; (void)ws_size;
  match_kernel<<<dim3(128), dim3(1024), 0, stream>>>(
      (const float*)d_in[0],   // passage
      (const float*)d_in[1],   // question
      (const float*)d_in[2],   // whq_w
      (const float*)d_in[3],   // whq_b
      (const float*)d_in[4],   // whp_w
      (const float*)d_in[5],   // whp_b
      (const float*)d_in[6],   // whr_w
      (const float*)d_in[7],   // whr_b
      (const float*)d_in[8],   // w_w
      (const float*)d_in[10],  // fw_Wih
      (const float*)d_in[11],  // fw_Whh
      (const float*)d_in[12],  // fw_bih
      (const float*)d_in[13],  // fw_bhh
      (const float*)d_in[14],  // bw_Wih
      (const float*)d_in[15],  // bw_Whh
      (const float*)d_in[16],  // bw_bih
      (const float*)d_in[17],  // bw_bhh
      (float*)d_out);
}

// Round 9
// 27619.284 us; speedup vs baseline: 1.0498x; 1.0498x over previous
//
#include <hip/hip_runtime.h>

#define HN 256
#define QN 64
#define PN 512
#define CH 8

typedef float f4 __attribute__((ext_vector_type(4)));

__device__ __forceinline__ float dot4(f4 a, f4 b) {
  return a.x * b.x + a.y * b.y + a.z * b.z + a.w * b.w;
}
__device__ __forceinline__ float fast_sig(float x) {
  return __builtin_amdgcn_rcpf(1.f + __builtin_amdgcn_exp2f(-1.44269504f * x));
}
__device__ __forceinline__ float fast_tanh(float x) {
  return 1.f - 2.f * __builtin_amdgcn_rcpf(1.f + __builtin_amdgcn_exp2f(2.88539008f * x));
}

struct SMem {
  union {
    float q32[QN][HN];                  // 64KB (prologue only)
    struct {
      alignas(16) float pgc[CH][1024];  // 32KB  Wih[:,0:256] @ p_u
      alignas(16) float wpc[CH][HN];    // 8KB   whp_b + whp_w @ p_u
      alignas(16) float pch[CH][HN];    // 8KB   p rows (f32)
    } c;
  } u;
  alignas(16) float wqt[QN][HN + 4];    // 65KB  wq table (persists all steps)
  alignas(16) float ww[HN];             // 1KB  w_w staged
  alignas(16) float hx[HN];
  float cx[HN];
  alignas(16) float wA[HN];
  float wrb[HN];                        // whr_b staged
  float gates[1024];
  float scores[QN];
  alignas(16) float al[QN];
};
static_assert(sizeof(SMem) <= 160 * 1024, "LDS overflow");
static_assert(sizeof(SMem) > 80 * 1024, "want exactly 1 block/CU");

__global__ void __launch_bounds__(1024, 4)
match_kernel(const float* __restrict__ passage, const float* __restrict__ question,
             const float* __restrict__ whq_w, const float* __restrict__ whq_b,
             const float* __restrict__ whp_w, const float* __restrict__ whp_b,
             const float* __restrict__ whr_w, const float* __restrict__ whr_b,
             const float* __restrict__ w_w,
             const float* __restrict__ Wih_f, const float* __restrict__ Whh_f,
             const float* __restrict__ bih_f, const float* __restrict__ bhh_f,
             const float* __restrict__ Wih_b, const float* __restrict__ Whh_b,
             const float* __restrict__ bih_b, const float* __restrict__ bhh_b,
             float* __restrict__ out)
{
  __shared__ SMem sm;
  const int t = threadIdx.x;
  const int bid = blockIdx.x;
  // dir-homogeneous XCD mapping: XCD = bid%8; XCD 0-3 -> dir0, 4-7 -> dir1
  const int e = bid & 7;
  const int dir = e >> 2;
  const int b = ((bid >> 3) << 2) | (e & 3);

  const float* Wih = dir ? Wih_b : Wih_f;
  const float* Whh = dir ? Whh_b : Whh_f;
  const float* bih = dir ? bih_b : bih_f;
  const float* bhh = dir ? bhh_b : bhh_f;

  const int qB = t >> 4;   // 0..63 (phase B q-owner; also row-group base g2)
  const int sg = t & 15;   // 16-lane slice id
  const int g2 = t >> 4;   // row-group base for sliced GEMVs

  // ---------------- prologue 1: stage question[b], init state ----------------
  {
    const int q = t >> 4, c0 = (t & 15) * 16;
    const float* src = question + ((size_t)b * QN + q) * HN + c0;
    #pragma unroll
    for (int m = 0; m < 4; ++m)
      *(f4*)&sm.u.q32[q][c0 + 4 * m] = *(const f4*)(src + 4 * m);
  }
  if (t < HN) {
    sm.hx[t] = 0.f; sm.cx[t] = 0.f;
    sm.wrb[t] = whr_b[t]; sm.ww[t] = w_w[t];
  }
  __syncthreads();

  // ---- prologue 2a: wqt[q][h] = whq_b[h] + sum_k Q[q][k]*whq_w[h][k] ----
  // 1024 threads: h = t&255, group (t>>8) in {0..3} handles 16 q's each.
  {
    const int h = t & 255, qh = (t >> 8) * 16;
    float acc[16];
    const float qb = whq_b[h];
    #pragma unroll
    for (int i2 = 0; i2 < 16; ++i2) acc[i2] = qb;
    const float* wrow = whq_w + (size_t)h * HN;
    for (int k = 0; k < HN; k += 4) {
      f4 w4 = *(const f4*)(wrow + k);
      #pragma unroll
      for (int i2 = 0; i2 < 16; ++i2) {
        f4 qv = *(const f4*)&sm.u.q32[qh + i2][k];
        acc[i2] += dot4(w4, qv);
      }
    }
    #pragma unroll
    for (int i2 = 0; i2 < 16; ++i2) sm.wqt[qh + i2][h] = acc[i2];
  }

  // ---------------- prologue 3: gq[r=t][q] = Wih[r, 256:512] . Q[q] ----------
  float gq[QN];
  #pragma unroll
  for (int q = 0; q < QN; ++q) gq[q] = 0.f;
  {
    const float* wrow = Wih + (size_t)t * 512 + 256;
    for (int i = 0; i < 64; ++i) {
      f4 w = *(const f4*)(wrow + 4 * i);
      #pragma unroll
      for (int q = 0; q < QN; ++q)
        gq[q] += dot4(w, *(const f4*)&sm.u.q32[q][4 * i]);
    }
  }
  const float biasr = bih[t] + bhh[t];
  __syncthreads();   // last readers of q32 done; union reused below

  const int tb = dir ? (PN - 1) : 0;
  const int ts = dir ? -1 : 1;

  for (int s = 0; s < PN; ++s) {
    const int tau = s & (CH - 1);
    if (tau == 0) {
      // ---- stage p chunk ----
      if (t < 512) {
        const int tt = t >> 6, cc = (t & 63) * 4;
        const int trow = tb + ts * (s + tt);
        *(f4*)&sm.u.c.pch[tt][cc] =
            *(const f4*)(passage + ((size_t)b * PN + trow) * HN + cc);
      }
      __syncthreads();
      // ---- wpc[u][h] = whp_b[h] + whp_w[h] . p_u  (rows 256, 4 sliced passes)
      #pragma unroll
      for (int rr = 0; rr < 4; ++rr) {
        const int h = g2 + 64 * rr;
        const float* wrow = whp_w + (size_t)h * HN + sg * 4;
        float acc[CH];
        #pragma unroll
        for (int uu = 0; uu < CH; ++uu) acc[uu] = 0.f;
        #pragma unroll
        for (int m = 0; m < 4; ++m) {
          f4 w = *(const f4*)(wrow + m * 64);
          #pragma unroll
          for (int uu = 0; uu < CH; ++uu)
            acc[uu] += dot4(w, *(const f4*)&sm.u.c.pch[uu][m * 64 + sg * 4]);
        }
        #pragma unroll
        for (int uu = 0; uu < CH; ++uu) {
          acc[uu] += __shfl_xor(acc[uu], 1);
          acc[uu] += __shfl_xor(acc[uu], 2);
          acc[uu] += __shfl_xor(acc[uu], 4);
          acc[uu] += __shfl_xor(acc[uu], 8);
        }
        if (sg == rr) {
          const float pb = whp_b[h];
          #pragma unroll
          for (int uu = 0; uu < CH; ++uu) sm.u.c.wpc[uu][h] = acc[uu] + pb;
        }
      }
      // ---- pgc[u][r] = Wih[r, 0:256] . p_u  (rows 1024, 16 sliced passes) ----
      #pragma unroll
      for (int rr = 0; rr < 16; ++rr) {
        const int r = g2 + 64 * rr;
        const float* wrow = Wih + (size_t)r * 512 + sg * 4;
        float acc[CH];
        #pragma unroll
        for (int uu = 0; uu < CH; ++uu) acc[uu] = 0.f;
        #pragma unroll
        for (int m = 0; m < 4; ++m) {
          f4 w = *(const f4*)(wrow + m * 64);
          #pragma unroll
          for (int uu = 0; uu < CH; ++uu)
            acc[uu] += dot4(w, *(const f4*)&sm.u.c.pch[uu][m * 64 + sg * 4]);
        }
        #pragma unroll
        for (int uu = 0; uu < CH; ++uu) {
          acc[uu] += __shfl_xor(acc[uu], 1);
          acc[uu] += __shfl_xor(acc[uu], 2);
          acc[uu] += __shfl_xor(acc[uu], 4);
          acc[uu] += __shfl_xor(acc[uu], 8);
        }
        if (sg == rr) {
          #pragma unroll
          for (int uu = 0; uu < CH; ++uu) sm.u.c.pgc[uu][r] = acc[uu];
        }
      }
      __syncthreads();
    }

    // ---- Phase A: wA[h] = whr_w[h].hx + wpc[tau][h] + whr_b[h] ----
    #pragma unroll
    for (int rr = 0; rr < 4; ++rr) {
      const int h = g2 + 64 * rr;
      const float* wrow = whr_w + (size_t)h * HN + sg * 4;
      float a = 0.f;
      #pragma unroll
      for (int m = 0; m < 4; ++m)
        a += dot4(*(const f4*)(wrow + m * 64),
                  *(const f4*)&sm.hx[m * 64 + sg * 4]);
      a += __shfl_xor(a, 1);
      a += __shfl_xor(a, 2);
      a += __shfl_xor(a, 4);
      a += __shfl_xor(a, 8);
      if (sg == rr) sm.wA[h] = a + sm.u.c.wpc[tau][h] + sm.wrb[h];
    }
    __syncthreads();

    // ---- Phase B: scores[q] = sum_h tanh(wqt[q][h] + wA[h]) * ww[h] ----
    {
      float sc = 0.f;
      #pragma unroll
      for (int jj = 0; jj < 4; ++jj) {
        f4 a4 = *(const f4*)&sm.wA[sg * 16 + 4 * jj];
        f4 q4 = *(const f4*)&sm.wqt[qB][sg * 16 + 4 * jj];
        f4 w4 = *(const f4*)&sm.ww[sg * 16 + 4 * jj];
        sc += fast_tanh(q4.x + a4.x) * w4.x;
        sc += fast_tanh(q4.y + a4.y) * w4.y;
        sc += fast_tanh(q4.z + a4.z) * w4.z;
        sc += fast_tanh(q4.w + a4.w) * w4.w;
      }
      sc += __shfl_xor(sc, 1);
      sc += __shfl_xor(sc, 2);
      sc += __shfl_xor(sc, 4);
      sc += __shfl_xor(sc, 8);
      if (sg == 0) sm.scores[qB] = sc;
    }
    __syncthreads();

    // ---- Phase C (wave 0) || Phase E1 (all): Whh[r].hx slice-GEMV ----
    #pragma unroll
    for (int rr = 0; rr < 16; ++rr) {
      const int r = g2 + 64 * rr;
      const float* wrow = Whh + (size_t)r * HN + sg * 4;
      float a = 0.f;
      #pragma unroll
      for (int m = 0; m < 4; ++m)
        a += dot4(*(const f4*)(wrow + m * 64),
                  *(const f4*)&sm.hx[m * 64 + sg * 4]);
      a += __shfl_xor(a, 1);
      a += __shfl_xor(a, 2);
      a += __shfl_xor(a, 4);
      a += __shfl_xor(a, 8);
      if (sg == rr) sm.gates[r] = a;
    }
    if (t < 64) {  // softmax over q; w_b dropped (shift-invariant)
      float sv = sm.scores[t];
      float mx = sv;
      #pragma unroll
      for (int o = 1; o < 64; o <<= 1) mx = fmaxf(mx, __shfl_xor(mx, o));
      float ex = __builtin_amdgcn_exp2f(1.44269504f * (sv - mx));
      float sum = ex;
      #pragma unroll
      for (int o = 1; o < 64; o <<= 1) sum += __shfl_xor(sum, o);
      sm.al[t] = ex * __builtin_amdgcn_rcpf(sum);
    }
    __syncthreads();

    // ---- Phase E2: gates[r=t] += pgc + bias + Gq[r].alpha ----
    {
      float acc = sm.gates[t] + sm.u.c.pgc[tau][t] + biasr;
      #pragma unroll
      for (int jj = 0; jj < 16; ++jj) {
        f4 av = *(const f4*)&sm.al[4 * jj];
        acc += gq[4 * jj + 0] * av.x + gq[4 * jj + 1] * av.y
             + gq[4 * jj + 2] * av.z + gq[4 * jj + 3] * av.w;
      }
      sm.gates[t] = acc;
    }
    __syncthreads();

    // ---- Phase F: LSTM elementwise + f32 output ----
    if (t < HN) {
      float gi = sm.gates[t], gf = sm.gates[HN + t];
      float gg = sm.gates[2 * HN + t], go = sm.gates[3 * HN + t];
      float c = fast_sig(gf) * sm.cx[t] + fast_sig(gi) * fast_tanh(gg);
      float hn = fast_sig(go) * fast_tanh(c);
      sm.cx[t] = c;
      sm.hx[t] = hn;
      const int trow = tb + ts * s;
      out[((size_t)trow * 64 + b) * 512 + dir * HN + t] = hn;
    }
    __syncthreads();
  }
}

extern "C" void kernel_launch(void* const* d_in, const int* in_sizes, int n_in,
                              void* d_out, int out_size, void* d_ws, size_t ws_size,
                              hipStream_t stream) {
  (void)in_sizes; (void)n_in; (void)out_size; (void)d_ws; (void)ws_size;
  match_kernel<<<dim3(128), dim3(1024), 0, stream>>>(
      (const float*)d_in[0],   // passage
      (const float*)d_in[1],   // question
      (const float*)d_in[2],   // whq_w
      (const float*)d_in[3],   // whq_b
      (const float*)d_in[4],   // whp_w
      (const float*)d_in[5],   // whp_b
      (const float*)d_in[6],   // whr_w
      (const float*)d_in[7],   // whr_b
      (const float*)d_in[8],   // w_w
      (const float*)d_in[10],  // fw_Wih
      (const float*)d_in[11],  // fw_Whh
      (const float*)d_in[12],  // fw_bih
      (const float*)d_in[13],  // fw_bhh
      (const float*)d_in[14],  // bw_Wih
      (const float*)d_in[15],  // bw_Whh
      (const float*)d_in[16],  // bw_bih
      (const float*)d_in[17],  // bw_bhh
      (float*)d_out);
}

// Round 10
// 26329.556 us; speedup vs baseline: 1.1012x; 1.0490x over previous
//
#include <hip/hip_runtime.h>

#define HN 256
#define QN 64
#define PN 512
#define CH 8

typedef float f4 __attribute__((ext_vector_type(4)));

__device__ __forceinline__ float dot4(f4 a, f4 b) {
  return a.x * b.x + a.y * b.y + a.z * b.z + a.w * b.w;
}
__device__ __forceinline__ float fast_sig(float x) {
  return __builtin_amdgcn_rcpf(1.f + __builtin_amdgcn_exp2f(-1.44269504f * x));
}
__device__ __forceinline__ float fast_tanh(float x) {
  return 1.f - 2.f * __builtin_amdgcn_rcpf(1.f + __builtin_amdgcn_exp2f(2.88539008f * x));
}

struct SMem {
  union {
    float q32[QN][HN];                  // 64KB (prologue only)
    struct {
      alignas(16) float pgc[CH][1024];  // 32KB  Wih[:,0:256] @ p_u
      alignas(16) float wpc[CH][HN];    // 8KB   whp_b + whp_w @ p_u
      alignas(16) float pch[CH][HN];    // 8KB   p rows (f32)
    } c;
  } u;
  alignas(16) float wqt[QN][HN + 4];    // 65KB  wq table (persists all steps)
  alignas(16) float ww[HN];             // 1KB  w_w staged
  alignas(16) float hx[HN];
  float cx[HN];
  alignas(16) float wA[HN];
  float wrb[HN];                        // whr_b staged
  float gates[1024];
  float scores[QN];
  alignas(16) float al[QN];
};
static_assert(sizeof(SMem) <= 160 * 1024, "LDS overflow");
static_assert(sizeof(SMem) > 80 * 1024, "want exactly 1 block/CU");

// amdgpu_waves_per_eu(4,4): LDS already caps us at 1 block/CU = 4 waves/EU.
// Setting MAX=4 stops the allocator from targeting 8 waves/EU (64 VGPRs),
// unlocking the 128-VGPR budget so gq[64] stays in registers (r6/r9: spilled).
__global__ void
__attribute__((amdgpu_flat_work_group_size(1024, 1024)))
__attribute__((amdgpu_waves_per_eu(4, 4)))
match_kernel(const float* __restrict__ passage, const float* __restrict__ question,
             const float* __restrict__ whq_w, const float* __restrict__ whq_b,
             const float* __restrict__ whp_w, const float* __restrict__ whp_b,
             const float* __restrict__ whr_w, const float* __restrict__ whr_b,
             const float* __restrict__ w_w,
             const float* __restrict__ Wih_f, const float* __restrict__ Whh_f,
             const float* __restrict__ bih_f, const float* __restrict__ bhh_f,
             const float* __restrict__ Wih_b, const float* __restrict__ Whh_b,
             const float* __restrict__ bih_b, const float* __restrict__ bhh_b,
             float* __restrict__ out)
{
  __shared__ SMem sm;
  const int t = threadIdx.x;
  const int bid = blockIdx.x;
  // dir-homogeneous XCD mapping: XCD = bid%8; XCD 0-3 -> dir0, 4-7 -> dir1
  const int e = bid & 7;
  const int dir = e >> 2;
  const int b = ((bid >> 3) << 2) | (e & 3);

  const float* Wih = dir ? Wih_b : Wih_f;
  const float* Whh = dir ? Whh_b : Whh_f;
  const float* bih = dir ? bih_b : bih_f;
  const float* bhh = dir ? bhh_b : bhh_f;

  const int qB = t >> 4;   // 0..63 (phase B q-owner; also row-group base g2)
  const int sg = t & 15;   // 16-lane slice id
  const int g2 = t >> 4;   // row-group base for sliced GEMVs

  // ---------------- prologue 1: stage question[b], init state ----------------
  {
    const int q = t >> 4, c0 = (t & 15) * 16;
    const float* src = question + ((size_t)b * QN + q) * HN + c0;
    #pragma unroll
    for (int m = 0; m < 4; ++m)
      *(f4*)&sm.u.q32[q][c0 + 4 * m] = *(const f4*)(src + 4 * m);
  }
  if (t < HN) {
    sm.hx[t] = 0.f; sm.cx[t] = 0.f;
    sm.wrb[t] = whr_b[t]; sm.ww[t] = w_w[t];
  }
  __syncthreads();

  // ---- prologue 2a: wqt[q][h] = whq_b[h] + sum_k Q[q][k]*whq_w[h][k] ----
  // 1024 threads: h = t&255, group (t>>8) in {0..3} handles 16 q's each.
  {
    const int h = t & 255, qh = (t >> 8) * 16;
    float acc[16];
    const float qb = whq_b[h];
    #pragma unroll
    for (int i2 = 0; i2 < 16; ++i2) acc[i2] = qb;
    const float* wrow = whq_w + (size_t)h * HN;
    for (int k = 0; k < HN; k += 4) {
      f4 w4 = *(const f4*)(wrow + k);
      #pragma unroll
      for (int i2 = 0; i2 < 16; ++i2) {
        f4 qv = *(const f4*)&sm.u.q32[qh + i2][k];
        acc[i2] += dot4(w4, qv);
      }
    }
    #pragma unroll
    for (int i2 = 0; i2 < 16; ++i2) sm.wqt[qh + i2][h] = acc[i2];
  }

  // ---------------- prologue 3: gq[r=t][q] = Wih[r, 256:512] . Q[q] ----------
  float gq[QN];
  #pragma unroll
  for (int q = 0; q < QN; ++q) gq[q] = 0.f;
  {
    const float* wrow = Wih + (size_t)t * 512 + 256;
    for (int i = 0; i < 64; ++i) {
      f4 w = *(const f4*)(wrow + 4 * i);
      #pragma unroll
      for (int q = 0; q < QN; ++q)
        gq[q] += dot4(w, *(const f4*)&sm.u.q32[q][4 * i]);
    }
  }
  const float biasr = bih[t] + bhh[t];
  __syncthreads();   // last readers of q32 done; union reused below

  const int tb = dir ? (PN - 1) : 0;
  const int ts = dir ? -1 : 1;

  for (int s = 0; s < PN; ++s) {
    const int tau = s & (CH - 1);
    if (tau == 0) {
      // ---- stage p chunk ----
      if (t < 512) {
        const int tt = t >> 6, cc = (t & 63) * 4;
        const int trow = tb + ts * (s + tt);
        *(f4*)&sm.u.c.pch[tt][cc] =
            *(const f4*)(passage + ((size_t)b * PN + trow) * HN + cc);
      }
      __syncthreads();
      // ---- wpc[u][h] = whp_b[h] + whp_w[h] . p_u  (rows 256, 4 sliced passes)
      #pragma unroll
      for (int rr = 0; rr < 4; ++rr) {
        const int h = g2 + 64 * rr;
        const float* wrow = whp_w + (size_t)h * HN + sg * 4;
        float acc[CH];
        #pragma unroll
        for (int uu = 0; uu < CH; ++uu) acc[uu] = 0.f;
        #pragma unroll
        for (int m = 0; m < 4; ++m) {
          f4 w = *(const f4*)(wrow + m * 64);
          #pragma unroll
          for (int uu = 0; uu < CH; ++uu)
            acc[uu] += dot4(w, *(const f4*)&sm.u.c.pch[uu][m * 64 + sg * 4]);
        }
        #pragma unroll
        for (int uu = 0; uu < CH; ++uu) {
          acc[uu] += __shfl_xor(acc[uu], 1);
          acc[uu] += __shfl_xor(acc[uu], 2);
          acc[uu] += __shfl_xor(acc[uu], 4);
          acc[uu] += __shfl_xor(acc[uu], 8);
        }
        if (sg == rr) {
          const float pb = whp_b[h];
          #pragma unroll
          for (int uu = 0; uu < CH; ++uu) sm.u.c.wpc[uu][h] = acc[uu] + pb;
        }
      }
      // ---- pgc[u][r] = Wih[r, 0:256] . p_u  (rows 1024, 16 sliced passes) ----
      #pragma unroll
      for (int rr = 0; rr < 16; ++rr) {
        const int r = g2 + 64 * rr;
        const float* wrow = Wih + (size_t)r * 512 + sg * 4;
        float acc[CH];
        #pragma unroll
        for (int uu = 0; uu < CH; ++uu) acc[uu] = 0.f;
        #pragma unroll
        for (int m = 0; m < 4; ++m) {
          f4 w = *(const f4*)(wrow + m * 64);
          #pragma unroll
          for (int uu = 0; uu < CH; ++uu)
            acc[uu] += dot4(w, *(const f4*)&sm.u.c.pch[uu][m * 64 + sg * 4]);
        }
        #pragma unroll
        for (int uu = 0; uu < CH; ++uu) {
          acc[uu] += __shfl_xor(acc[uu], 1);
          acc[uu] += __shfl_xor(acc[uu], 2);
          acc[uu] += __shfl_xor(acc[uu], 4);
          acc[uu] += __shfl_xor(acc[uu], 8);
        }
        if (sg == rr) {
          #pragma unroll
          for (int uu = 0; uu < CH; ++uu) sm.u.c.pgc[uu][r] = acc[uu];
        }
      }
      __syncthreads();
    }

    // ---- Phase A: wA[h] = whr_w[h].hx + wpc[tau][h] + whr_b[h] ----
    #pragma unroll
    for (int rr = 0; rr < 4; ++rr) {
      const int h = g2 + 64 * rr;
      const float* wrow = whr_w + (size_t)h * HN + sg * 4;
      float a = 0.f;
      #pragma unroll
      for (int m = 0; m < 4; ++m)
        a += dot4(*(const f4*)(wrow + m * 64),
                  *(const f4*)&sm.hx[m * 64 + sg * 4]);
      a += __shfl_xor(a, 1);
      a += __shfl_xor(a, 2);
      a += __shfl_xor(a, 4);
      a += __shfl_xor(a, 8);
      if (sg == rr) sm.wA[h] = a + sm.u.c.wpc[tau][h] + sm.wrb[h];
    }
    __syncthreads();

    // ---- Phase B: scores[q] = sum_h tanh(wqt[q][h] + wA[h]) * ww[h] ----
    {
      float sc = 0.f;
      #pragma unroll
      for (int jj = 0; jj < 4; ++jj) {
        f4 a4 = *(const f4*)&sm.wA[sg * 16 + 4 * jj];
        f4 q4 = *(const f4*)&sm.wqt[qB][sg * 16 + 4 * jj];
        f4 w4 = *(const f4*)&sm.ww[sg * 16 + 4 * jj];
        sc += fast_tanh(q4.x + a4.x) * w4.x;
        sc += fast_tanh(q4.y + a4.y) * w4.y;
        sc += fast_tanh(q4.z + a4.z) * w4.z;
        sc += fast_tanh(q4.w + a4.w) * w4.w;
      }
      sc += __shfl_xor(sc, 1);
      sc += __shfl_xor(sc, 2);
      sc += __shfl_xor(sc, 4);
      sc += __shfl_xor(sc, 8);
      if (sg == 0) sm.scores[qB] = sc;
    }
    __syncthreads();

    // ---- Phase C (wave 0) || Phase E1 (all): Whh[r].hx slice-GEMV ----
    #pragma unroll
    for (int rr = 0; rr < 16; ++rr) {
      const int r = g2 + 64 * rr;
      const float* wrow = Whh + (size_t)r * HN + sg * 4;
      float a = 0.f;
      #pragma unroll
      for (int m = 0; m < 4; ++m)
        a += dot4(*(const f4*)(wrow + m * 64),
                  *(const f4*)&sm.hx[m * 64 + sg * 4]);
      a += __shfl_xor(a, 1);
      a += __shfl_xor(a, 2);
      a += __shfl_xor(a, 4);
      a += __shfl_xor(a, 8);
      if (sg == rr) sm.gates[r] = a;
    }
    if (t < 64) {  // softmax over q; w_b dropped (shift-invariant)
      float sv = sm.scores[t];
      float mx = sv;
      #pragma unroll
      for (int o = 1; o < 64; o <<= 1) mx = fmaxf(mx, __shfl_xor(mx, o));
      float ex = __builtin_amdgcn_exp2f(1.44269504f * (sv - mx));
      float sum = ex;
      #pragma unroll
      for (int o = 1; o < 64; o <<= 1) sum += __shfl_xor(sum, o);
      sm.al[t] = ex * __builtin_amdgcn_rcpf(sum);
    }
    __syncthreads();

    // ---- Phase E2: gates[r=t] += pgc + bias + Gq[r].alpha ----
    {
      float acc = sm.gates[t] + sm.u.c.pgc[tau][t] + biasr;
      #pragma unroll
      for (int jj = 0; jj < 16; ++jj) {
        f4 av = *(const f4*)&sm.al[4 * jj];
        acc += gq[4 * jj + 0] * av.x + gq[4 * jj + 1] * av.y
             + gq[4 * jj + 2] * av.z + gq[4 * jj + 3] * av.w;
      }
      sm.gates[t] = acc;
    }
    __syncthreads();

    // ---- Phase F: LSTM elementwise + f32 output ----
    if (t < HN) {
      float gi = sm.gates[t], gf = sm.gates[HN + t];
      float gg = sm.gates[2 * HN + t], go = sm.gates[3 * HN + t];
      float c = fast_sig(gf) * sm.cx[t] + fast_sig(gi) * fast_tanh(gg);
      float hn = fast_sig(go) * fast_tanh(c);
      sm.cx[t] = c;
      sm.hx[t] = hn;
      const int trow = tb + ts * s;
      out[((size_t)trow * 64 + b) * 512 + dir * HN + t] = hn;
    }
    __syncthreads();
  }
}

extern "C" void kernel_launch(void* const* d_in, const int* in_sizes, int n_in,
                              void* d_out, int out_size, void* d_ws, size_t ws_size,
                              hipStream_t stream) {
  (void)in_sizes; (void)n_in; (void)out_size; (void)d_ws; (void)ws_size;
  match_kernel<<<dim3(128), dim3(1024), 0, stream>>>(
      (const float*)d_in[0],   // passage
      (const float*)d_in[1],   // question
      (const float*)d_in[2],   // whq_w
      (const float*)d_in[3],   // whq_b
      (const float*)d_in[4],   // whp_w
      (const float*)d_in[5],   // whp_b
      (const float*)d_in[6],   // whr_w
      (const float*)d_in[7],   // whr_b
      (const float*)d_in[8],   // w_w
      (const float*)d_in[10],  // fw_Wih
      (const float*)d_in[11],  // fw_Whh
      (const float*)d_in[12],  // fw_bih
      (const float*)d_in[13],  // fw_bhh
      (const float*)d_in[14],  // bw_Wih
      (const float*)d_in[15],  // bw_Whh
      (const float*)d_in[16],  // bw_bih
      (const float*)d_in[17],  // bw_bhh
      (float*)d_out);
}